// Round 8
// baseline (297.575 us; speedup 1.0000x reference)
//
#include <hip/hip_runtime.h>
#include <hip/hip_bf16.h>

// S=8192, D_IN=512, D_OUT=64. O = softmax(tril(QK^T)/8) @ V.
// Round 8: TWO ordinary dispatches.
//  1) proj: fp32 x & W read directly (casts folded); W converted+staged into
//     swizzled LDS; writes Q(*1/8),K bf16 row-major + V^T bf16; zeroes counters.
//  2) attn: R6-validated staged split-K flash + last-done-block reduction
//     epilogue (device-scope fence/atomic; dispatch-order-safe, G16-OK).

typedef __attribute__((ext_vector_type(8))) short short8;   // 8 bf16 MFMA A/B frag
typedef __attribute__((ext_vector_type(4))) float f32x4;    // MFMA C/D frag
typedef __attribute__((ext_vector_type(4))) float f4v;

__device__ inline unsigned int pk2(float a, float b) {
    union { __hip_bfloat162 h; unsigned int u; } v;
    v.h = __float22bfloat162_rn(make_float2(a, b));
    return v.u;
}
__device__ inline void gload_lds16(const void* g, void* l) {
    __builtin_amdgcn_global_load_lds(
        (const __attribute__((address_space(1))) unsigned int*)g,
        (__attribute__((address_space(3))) unsigned int*)l, 16, 0, 0);
}

// Q-blocks of 128 rows, parts of 512 cols: np(qb) = (qb>>2)+1.
// base(qb) = qb + 2g(g-1) + (qb&3)*g, g = qb>>2. Total slots = 544.
__device__ inline int part_base(int qb) {
    int g = qb >> 2;
    return qb + 2 * g * (g - 1) + (qb & 3) * g;
}

// ---------------- QKV projection, all casts folded ----------------
// grid (128, 3): x = 64-row block, y = mat. 4 waves, 16 rows each.
// W_mat (fp32) converted to bf16 while staging into swizzled LDS.
__global__ __launch_bounds__(256) void proj_kernel(const float* __restrict__ x,
                                                   const float* __restrict__ wq,
                                                   const float* __restrict__ wk,
                                                   const float* __restrict__ wv,
                                                   unsigned short* __restrict__ qb,
                                                   unsigned short* __restrict__ kb,
                                                   unsigned short* __restrict__ vt,
                                                   int* __restrict__ cnt) {
    __shared__ unsigned short lds_w[64 * 512];   // 64KB bf16 W_mat, chunk^=(row&7)
    const int tid = threadIdx.x;
    const int wave = tid >> 6, lane = tid & 63;
    const int l16 = lane & 15, quad = lane >> 4;
    const int mat = blockIdx.y;
    const int r0 = blockIdx.x * 64 + wave * 16;
    const float* wm = (mat == 0) ? wq : ((mat == 1) ? wk : wv);

    if (blockIdx.x == 0 && mat == 0 && tid < 64) cnt[tid] = 0;   // task counters

    // stage + convert W_mat: 4096 chunks of 8 bf16; LDS chunk idx holds
    // global chunk (row=idx>>6, gc=(idx&63)^(row&7))
#pragma unroll
    for (int j = 0; j < 16; ++j) {
        const int idx = j * 256 + tid;
        const int row = idx >> 6;
        const int gc = (idx & 63) ^ (row & 7);
        f4v v0 = *(const f4v*)(wm + row * 512 + gc * 8);
        f4v v1 = *(const f4v*)(wm + row * 512 + gc * 8 + 4);
        union { short8 s; unsigned int u[4]; } pv;
        pv.u[0] = pk2(v0.x, v0.y); pv.u[1] = pk2(v0.z, v0.w);
        pv.u[2] = pk2(v1.x, v1.y); pv.u[3] = pk2(v1.z, v1.w);
        *(short8*)(lds_w + idx * 8) = pv.s;
    }
    __syncthreads();

    const float* xr = x + (r0 + l16) * 512 + quad * 8;
    f32x4 acc[4] = {};
    for (int kc = 0; kc < 16; ++kc) {
        f4v a0 = *(const f4v*)(xr + kc * 32);
        f4v a1 = *(const f4v*)(xr + kc * 32 + 4);
        union { short8 s; unsigned int u[4]; } av;
        av.u[0] = pk2(a0.x, a0.y); av.u[1] = pk2(a0.z, a0.w);
        av.u[2] = pk2(a1.x, a1.y); av.u[3] = pk2(a1.z, a1.w);
#pragma unroll
        for (int c = 0; c < 4; ++c) {
            short8 b = *(const short8*)(lds_w + (c * 16 + l16) * 512 +
                                        (((kc * 4 + quad) ^ (l16 & 7)) * 8));
            acc[c] = __builtin_amdgcn_mfma_f32_16x16x32_bf16(av.s, b, acc[c], 0, 0, 0);
        }
    }
    const float scale = (mat == 0) ? 0.125f : 1.0f;   // fold 1/sqrt(d_k) into Q
#pragma unroll
    for (int c = 0; c < 4; ++c)
#pragma unroll
        for (int r = 0; r < 4; ++r) {
            const int row = r0 + quad * 4 + r;   // C/D: row=(lane>>4)*4+reg, col=lane&15
            const int col = c * 16 + l16;
            union { __hip_bfloat16 h; unsigned short u; } hv;
            hv.h = __float2bfloat16(acc[c][r] * scale);
            if (mat == 0)       qb[row * 64 + col] = hv.u;
            else if (mat == 1)  kb[row * 64 + col] = hv.u;
            else                vt[col * 8192 + row] = hv.u;   // V^T [64][8192]
        }
}

// ---------------- staged split-K flash attention + fused combine ----------------
// grid (16, 64), 256 thr. blockIdx.y = qb (128 Q rows), x = part (512 cols).
// Body identical to R6 (validated). Epilogue: last-done block per qb reduces.
__global__ __launch_bounds__(256) void attn_kernel(const unsigned short* __restrict__ qbuf,
                                                   const unsigned short* __restrict__ kbuf,
                                                   const unsigned short* __restrict__ vt,
                                                   float* __restrict__ O_part,
                                                   float* __restrict__ l_part,
                                                   int* __restrict__ cnt,
                                                   float* __restrict__ out) {
    const int qb_i = blockIdx.y;
    const int part = blockIdx.x;
    const int g = qb_i >> 2;
    if (part > g) return;                         // np = g+1; block-uniform exit

    __shared__ unsigned short lds_k[64 * 64];     // [row][64], chunk^=(row&7)
    __shared__ unsigned short lds_v[64 * 64];     // V^T tile [dim][64], chunk^=(dim&7)
    __shared__ unsigned short lds_p[4][32 * 72];  // per-wave P, stride 72
    __shared__ float Ls[128];
    __shared__ int isLast;

    const int tid = threadIdx.x;
    const int wave = tid >> 6, lane = tid & 63;
    const int l16 = lane & 15, quad = lane >> 4;
    const int q0 = qb_i * 128;
    const int q0w = q0 + wave * 32;
    const int c0 = part * 512;
    const int cend = min(c0 + 512, q0 + 128);     // 64-aligned
    const int ntiles = (cend - c0) >> 6;
    unsigned short* lp = lds_p[wave];

    f32x4 o[2][4] = {};
    float ls[2] = {0.f, 0.f};

    // Q B-frags (resident)
    short8 qf[2][2];
#pragma unroll
    for (int cg = 0; cg < 2; ++cg)
#pragma unroll
        for (int kg = 0; kg < 2; ++kg)
            qf[cg][kg] = *(const short8*)(qbuf + (q0w + cg * 16 + l16) * 64 + kg * 32 + quad * 8);

    for (int it = 0; it < ntiles; ++it) {
        const int kc0 = c0 + it * 64;
#pragma unroll
        for (int s = 0; s < 2; ++s) {
            const int idx = (wave * 2 + s) * 64 + lane;   // 0..511
            const int srow = idx >> 3;
            const int scc = (idx & 7) ^ (srow & 7);
            gload_lds16(kbuf + (kc0 + srow) * 64 + scc * 8, lds_k + idx * 8);
            gload_lds16(vt + srow * 8192 + kc0 + scc * 8,   lds_v + idx * 8);
        }
        __syncthreads();

        if (kc0 <= q0w + 31) {                    // wave-uniform compute guard
            short8 af[4][2], vf[4][2];
#pragma unroll
            for (int rg = 0; rg < 4; ++rg)
#pragma unroll
                for (int kg = 0; kg < 2; ++kg)
                    af[rg][kg] = *(const short8*)(lds_k + (rg * 16 + l16) * 64 +
                                                  (((kg * 4 + quad) ^ (l16 & 7)) * 8));
#pragma unroll
            for (int ng = 0; ng < 4; ++ng)
#pragma unroll
                for (int kg = 0; kg < 2; ++kg)
                    vf[ng][kg] = *(const short8*)(lds_v + (ng * 16 + l16) * 64 +
                                                  (((kg * 4 + quad) ^ (l16 & 7)) * 8));

            // S^T = K Q^T: row=K-col kc0+rg*16+quad*4+r, col=Q-row q0w+cg*16+l16
            f32x4 st[4][2];
#pragma unroll
            for (int rg = 0; rg < 4; ++rg)
#pragma unroll
                for (int cg = 0; cg < 2; ++cg) {
                    f32x4 z = {};
                    z          = __builtin_amdgcn_mfma_f32_16x16x32_bf16(af[rg][0], qf[cg][0], z, 0, 0, 0);
                    st[rg][cg] = __builtin_amdgcn_mfma_f32_16x16x32_bf16(af[rg][1], qf[cg][1], z, 0, 0, 0);
                }

            if (kc0 + 63 > q0w) {                 // diagonal tiles only
#pragma unroll
                for (int rg = 0; rg < 4; ++rg)
#pragma unroll
                    for (int cg = 0; cg < 2; ++cg)
#pragma unroll
                        for (int r = 0; r < 4; ++r) {
                            const int kcol = kc0 + rg * 16 + quad * 4 + r;
                            const int qrow = q0w + cg * 16 + l16;
                            if (kcol > qrow) st[rg][cg][r] = -3.0e38f;
                        }
            }

            // p = exp(s), no max subtraction (r3-validated)
#pragma unroll
            for (int rg = 0; rg < 4; ++rg)
#pragma unroll
                for (int cg = 0; cg < 2; ++cg)
#pragma unroll
                    for (int r = 0; r < 4; ++r) {
                        const float p = __expf(st[rg][cg][r]);
                        st[rg][cg][r] = p;
                        ls[cg] += p;
                    }

            // P -> per-wave LDS, stride 72
#pragma unroll
            for (int rg = 0; rg < 4; ++rg)
#pragma unroll
                for (int cg = 0; cg < 2; ++cg) {
                    uint2 w;
                    w.x = pk2(st[rg][cg][0], st[rg][cg][1]);
                    w.y = pk2(st[rg][cg][2], st[rg][cg][3]);
                    *(uint2*)(lp + (cg * 16 + l16) * 72 + rg * 16 + quad * 4) = w;
                }
            asm volatile("s_waitcnt lgkmcnt(0)" ::: "memory");
            short8 pa[2][2];
#pragma unroll
            for (int mg = 0; mg < 2; ++mg)
#pragma unroll
                for (int kg = 0; kg < 2; ++kg)
                    pa[mg][kg] = *(const short8*)(lp + (mg * 16 + l16) * 72 + kg * 32 + quad * 8);

#pragma unroll
            for (int mg = 0; mg < 2; ++mg)
#pragma unroll
                for (int ng = 0; ng < 4; ++ng) {
                    o[mg][ng] = __builtin_amdgcn_mfma_f32_16x16x32_bf16(pa[mg][0], vf[ng][0], o[mg][ng], 0, 0, 0);
                    o[mg][ng] = __builtin_amdgcn_mfma_f32_16x16x32_bf16(pa[mg][1], vf[ng][1], o[mg][ng], 0, 0, 0);
                }
        }
        __syncthreads();
    }

    // reduce ls over quads (Q-row lives in l16)
#pragma unroll
    for (int cg = 0; cg < 2; ++cg) {
        ls[cg] += __shfl_xor(ls[cg], 16, 64);
        ls[cg] += __shfl_xor(ls[cg], 32, 64);
    }

    const int base = part_base(qb_i);
    const int slot = base + part;
    float* Op = O_part + (size_t)slot * 8192;
#pragma unroll
    for (int mg = 0; mg < 2; ++mg)
#pragma unroll
        for (int ng = 0; ng < 4; ++ng)
#pragma unroll
            for (int r = 0; r < 4; ++r)
                Op[(wave * 32 + mg * 16 + quad * 4 + r) * 64 + ng * 16 + l16] = o[mg][ng][r];
    if (quad == 0) {
#pragma unroll
        for (int cg = 0; cg < 2; ++cg)
            l_part[slot * 128 + wave * 32 + cg * 16 + l16] = ls[cg];
    }

    // ---- last-done-block combine (release: fence+sync+atomic) ----
    __threadfence();
    __syncthreads();
    if (tid == 0) {
        const int old = atomicAdd(&cnt[qb_i], 1);
        isLast = (old == g) ? 1 : 0;
    }
    __syncthreads();
    if (isLast) {
        __threadfence();                          // acquire side
        const int np = g + 1;
        if (tid < 128) {
            float s = 0.0f;
            for (int p = 0; p < np; ++p) s += l_part[(base + p) * 128 + tid];
            Ls[tid] = s;
        }
        __syncthreads();
#pragma unroll
        for (int u = 0; u < 8; ++u) {
            const int e = u * 1024 + tid * 4;     // 8192 elements
            const int row = e >> 6;
            f4v acc = {0.f, 0.f, 0.f, 0.f};
            for (int p = 0; p < np; ++p)
                acc += *(const f4v*)(O_part + (size_t)(base + p) * 8192 + e);
            acc *= (1.0f / Ls[row]);
            *(f4v*)(out + (size_t)qb_i * 8192 + e) = acc;
        }
    }
}

extern "C" void kernel_launch(void* const* d_in, const int* in_sizes, int n_in,
                              void* d_out, int out_size, void* d_ws, size_t ws_size,
                              hipStream_t stream) {
    const float* x  = (const float*)d_in[0];
    const float* wq = (const float*)d_in[1];
    const float* wk = (const float*)d_in[2];
    const float* wv = (const float*)d_in[3];
    float* out = (float*)d_out;

    char* ws = (char*)d_ws;
    unsigned short* qb = (unsigned short*)(ws);               // 1,048,576 B
    unsigned short* kb = (unsigned short*)(ws + 1048576);     // 1,048,576 B
    unsigned short* vt = (unsigned short*)(ws + 2097152);     // 1,048,576 B (V^T [64][8192])
    float* O_part = (float*)(ws + 3145728);                   // 544*8192*4 = 17,825,792 B
    float* l_part = (float*)(ws + 20971520);                  // 544*128*4 = 278,528 B
    int*   cnt    = (int*)(ws + 21250048);                    // 64*4 = 256 B
    // total ws: 21,250,304 B

    proj_kernel<<<dim3(128, 3), 256, 0, stream>>>(x, wq, wk, wv, qb, kb, vt, cnt);
    attn_kernel<<<dim3(16, 64), 256, 0, stream>>>(qb, kb, vt, O_part, l_part, cnt, out);
}

// Round 9
// 133.608 us; speedup vs baseline: 2.2272x; 2.2272x over previous
//
#include <hip/hip_runtime.h>
#include <hip/hip_bf16.h>

// S=8192, D_IN=512, D_OUT=64. O = softmax(tril(QK^T)/8) @ V.
// Round 9: THREE dispatches. proj (R8, casts folded) -> attn (R6 byte-exact:
// staged split-K flash, nt partial stores, NO fence/atomic) -> reduce (R6).
// R8's in-kernel combine epilogue removed: its device-scope __threadfence
// (buffer_wbl2/inv = L2 flush) fired per-block and destroyed L2 residency.

typedef __attribute__((ext_vector_type(8))) short short8;   // 8 bf16 MFMA A/B frag
typedef __attribute__((ext_vector_type(4))) float f32x4;    // MFMA C/D frag
typedef __attribute__((ext_vector_type(4))) float f4v;

__device__ inline unsigned int pk2(float a, float b) {
    union { __hip_bfloat162 h; unsigned int u; } v;
    v.h = __float22bfloat162_rn(make_float2(a, b));
    return v.u;
}
__device__ inline void gload_lds16(const void* g, void* l) {
    __builtin_amdgcn_global_load_lds(
        (const __attribute__((address_space(1))) unsigned int*)g,
        (__attribute__((address_space(3))) unsigned int*)l, 16, 0, 0);
}

// Q-blocks of 128 rows, parts of 512 cols: np(qb) = (qb>>2)+1.
// base(qb) = qb + 2g(g-1) + (qb&3)*g, g = qb>>2. Total slots = 544.
__device__ inline int part_base(int qb) {
    int g = qb >> 2;
    return qb + 2 * g * (g - 1) + (qb & 3) * g;
}

// ---------------- QKV projection, all casts folded (R8-validated) ----------------
// grid (128, 3): x = 64-row block, y = mat. 4 waves, 16 rows each.
__global__ __launch_bounds__(256) void proj_kernel(const float* __restrict__ x,
                                                   const float* __restrict__ wq,
                                                   const float* __restrict__ wk,
                                                   const float* __restrict__ wv,
                                                   unsigned short* __restrict__ qb,
                                                   unsigned short* __restrict__ kb,
                                                   unsigned short* __restrict__ vt) {
    __shared__ unsigned short lds_w[64 * 512];   // 64KB bf16 W_mat, chunk^=(row&7)
    const int tid = threadIdx.x;
    const int wave = tid >> 6, lane = tid & 63;
    const int l16 = lane & 15, quad = lane >> 4;
    const int mat = blockIdx.y;
    const int r0 = blockIdx.x * 64 + wave * 16;
    const float* wm = (mat == 0) ? wq : ((mat == 1) ? wk : wv);

    // stage + convert W_mat: 4096 chunks of 8 bf16
#pragma unroll
    for (int j = 0; j < 16; ++j) {
        const int idx = j * 256 + tid;
        const int row = idx >> 6;
        const int gc = (idx & 63) ^ (row & 7);
        f4v v0 = *(const f4v*)(wm + row * 512 + gc * 8);
        f4v v1 = *(const f4v*)(wm + row * 512 + gc * 8 + 4);
        union { short8 s; unsigned int u[4]; } pv;
        pv.u[0] = pk2(v0.x, v0.y); pv.u[1] = pk2(v0.z, v0.w);
        pv.u[2] = pk2(v1.x, v1.y); pv.u[3] = pk2(v1.z, v1.w);
        *(short8*)(lds_w + idx * 8) = pv.s;
    }
    __syncthreads();

    const float* xr = x + (r0 + l16) * 512 + quad * 8;
    f32x4 acc[4] = {};
    for (int kc = 0; kc < 16; ++kc) {
        f4v a0 = *(const f4v*)(xr + kc * 32);
        f4v a1 = *(const f4v*)(xr + kc * 32 + 4);
        union { short8 s; unsigned int u[4]; } av;
        av.u[0] = pk2(a0.x, a0.y); av.u[1] = pk2(a0.z, a0.w);
        av.u[2] = pk2(a1.x, a1.y); av.u[3] = pk2(a1.z, a1.w);
#pragma unroll
        for (int c = 0; c < 4; ++c) {
            short8 b = *(const short8*)(lds_w + (c * 16 + l16) * 512 +
                                        (((kc * 4 + quad) ^ (l16 & 7)) * 8));
            acc[c] = __builtin_amdgcn_mfma_f32_16x16x32_bf16(av.s, b, acc[c], 0, 0, 0);
        }
    }
    const float scale = (mat == 0) ? 0.125f : 1.0f;   // fold 1/sqrt(d_k) into Q
#pragma unroll
    for (int c = 0; c < 4; ++c)
#pragma unroll
        for (int r = 0; r < 4; ++r) {
            const int row = r0 + quad * 4 + r;   // C/D: row=(lane>>4)*4+reg, col=lane&15
            const int col = c * 16 + l16;
            union { __hip_bfloat16 h; unsigned short u; } hv;
            hv.h = __float2bfloat16(acc[c][r] * scale);
            if (mat == 0)       qb[row * 64 + col] = hv.u;
            else if (mat == 1)  kb[row * 64 + col] = hv.u;
            else                vt[col * 8192 + row] = hv.u;   // V^T [64][8192]
        }
}

// ---------------- staged split-K flash attention (R6 byte-exact) ----------------
// grid (16, 64), 256 thr. blockIdx.y = qb (128 Q rows), x = part (512 cols).
__global__ __launch_bounds__(256) void attn_kernel(const unsigned short* __restrict__ qbuf,
                                                   const unsigned short* __restrict__ kbuf,
                                                   const unsigned short* __restrict__ vt,
                                                   float* __restrict__ O_part,
                                                   float* __restrict__ l_part) {
    const int qb_i = blockIdx.y;
    const int part = blockIdx.x;
    const int g = qb_i >> 2;
    if (part > g) return;                         // np = g+1; block-uniform exit

    __shared__ unsigned short lds_k[64 * 64];     // [row][64], chunk^=(row&7)
    __shared__ unsigned short lds_v[64 * 64];     // V^T tile [dim][64], chunk^=(dim&7)
    __shared__ unsigned short lds_p[4][32 * 72];  // per-wave P, stride 72

    const int tid = threadIdx.x;
    const int wave = tid >> 6, lane = tid & 63;
    const int l16 = lane & 15, quad = lane >> 4;
    const int q0 = qb_i * 128;
    const int q0w = q0 + wave * 32;
    const int c0 = part * 512;
    const int cend = min(c0 + 512, q0 + 128);     // 64-aligned
    const int ntiles = (cend - c0) >> 6;
    unsigned short* lp = lds_p[wave];

    f32x4 o[2][4] = {};
    float ls[2] = {0.f, 0.f};

    // Q B-frags (resident)
    short8 qf[2][2];
#pragma unroll
    for (int cg = 0; cg < 2; ++cg)
#pragma unroll
        for (int kg = 0; kg < 2; ++kg)
            qf[cg][kg] = *(const short8*)(qbuf + (q0w + cg * 16 + l16) * 64 + kg * 32 + quad * 8);

    for (int it = 0; it < ntiles; ++it) {
        const int kc0 = c0 + it * 64;
#pragma unroll
        for (int s = 0; s < 2; ++s) {
            const int idx = (wave * 2 + s) * 64 + lane;   // 0..511
            const int srow = idx >> 3;
            const int scc = (idx & 7) ^ (srow & 7);
            gload_lds16(kbuf + (kc0 + srow) * 64 + scc * 8, lds_k + idx * 8);
            gload_lds16(vt + srow * 8192 + kc0 + scc * 8,   lds_v + idx * 8);
        }
        __syncthreads();

        if (kc0 <= q0w + 31) {                    // wave-uniform compute guard
            short8 af[4][2], vf[4][2];
#pragma unroll
            for (int rg = 0; rg < 4; ++rg)
#pragma unroll
                for (int kg = 0; kg < 2; ++kg)
                    af[rg][kg] = *(const short8*)(lds_k + (rg * 16 + l16) * 64 +
                                                  (((kg * 4 + quad) ^ (l16 & 7)) * 8));
#pragma unroll
            for (int ng = 0; ng < 4; ++ng)
#pragma unroll
                for (int kg = 0; kg < 2; ++kg)
                    vf[ng][kg] = *(const short8*)(lds_v + (ng * 16 + l16) * 64 +
                                                  (((kg * 4 + quad) ^ (l16 & 7)) * 8));

            // S^T = K Q^T: row=K-col kc0+rg*16+quad*4+r, col=Q-row q0w+cg*16+l16
            f32x4 st[4][2];
#pragma unroll
            for (int rg = 0; rg < 4; ++rg)
#pragma unroll
                for (int cg = 0; cg < 2; ++cg) {
                    f32x4 z = {};
                    z          = __builtin_amdgcn_mfma_f32_16x16x32_bf16(af[rg][0], qf[cg][0], z, 0, 0, 0);
                    st[rg][cg] = __builtin_amdgcn_mfma_f32_16x16x32_bf16(af[rg][1], qf[cg][1], z, 0, 0, 0);
                }

            if (kc0 + 63 > q0w) {                 // diagonal tiles only
#pragma unroll
                for (int rg = 0; rg < 4; ++rg)
#pragma unroll
                    for (int cg = 0; cg < 2; ++cg)
#pragma unroll
                        for (int r = 0; r < 4; ++r) {
                            const int kcol = kc0 + rg * 16 + quad * 4 + r;
                            const int qrow = q0w + cg * 16 + l16;
                            if (kcol > qrow) st[rg][cg][r] = -3.0e38f;
                        }
            }

            // p = exp(s), no max subtraction (r3-validated)
#pragma unroll
            for (int rg = 0; rg < 4; ++rg)
#pragma unroll
                for (int cg = 0; cg < 2; ++cg)
#pragma unroll
                    for (int r = 0; r < 4; ++r) {
                        const float p = __expf(st[rg][cg][r]);
                        st[rg][cg][r] = p;
                        ls[cg] += p;
                    }

            // P -> per-wave LDS, stride 72
#pragma unroll
            for (int rg = 0; rg < 4; ++rg)
#pragma unroll
                for (int cg = 0; cg < 2; ++cg) {
                    uint2 w;
                    w.x = pk2(st[rg][cg][0], st[rg][cg][1]);
                    w.y = pk2(st[rg][cg][2], st[rg][cg][3]);
                    *(uint2*)(lp + (cg * 16 + l16) * 72 + rg * 16 + quad * 4) = w;
                }
            asm volatile("s_waitcnt lgkmcnt(0)" ::: "memory");
            short8 pa[2][2];
#pragma unroll
            for (int mg = 0; mg < 2; ++mg)
#pragma unroll
                for (int kg = 0; kg < 2; ++kg)
                    pa[mg][kg] = *(const short8*)(lp + (mg * 16 + l16) * 72 + kg * 32 + quad * 8);

#pragma unroll
            for (int mg = 0; mg < 2; ++mg)
#pragma unroll
                for (int ng = 0; ng < 4; ++ng) {
                    o[mg][ng] = __builtin_amdgcn_mfma_f32_16x16x32_bf16(pa[mg][0], vf[ng][0], o[mg][ng], 0, 0, 0);
                    o[mg][ng] = __builtin_amdgcn_mfma_f32_16x16x32_bf16(pa[mg][1], vf[ng][1], o[mg][ng], 0, 0, 0);
                }
        }
        __syncthreads();
    }

    // reduce ls over quads (Q-row lives in l16)
#pragma unroll
    for (int cg = 0; cg < 2; ++cg) {
        ls[cg] += __shfl_xor(ls[cg], 16, 64);
        ls[cg] += __shfl_xor(ls[cg], 32, 64);
    }

    const int slot = part_base(qb_i) + part;
    float* Op = O_part + (size_t)slot * 8192;
#pragma unroll
    for (int mg = 0; mg < 2; ++mg)
#pragma unroll
        for (int ng = 0; ng < 4; ++ng)
#pragma unroll
            for (int r = 0; r < 4; ++r)
                __builtin_nontemporal_store(o[mg][ng][r],
                    Op + (wave * 32 + mg * 16 + quad * 4 + r) * 64 + ng * 16 + l16);
    if (quad == 0) {
#pragma unroll
        for (int cg = 0; cg < 2; ++cg)
            __builtin_nontemporal_store(ls[cg],
                l_part + slot * 128 + wave * 32 + cg * 16 + l16);
    }
}

// ---------------- combine: sum partials, normalize (R6-validated) ----------------
// grid 256: 4 blocks per Q-block, 32 rows each.
__global__ __launch_bounds__(256) void attn_reduce_kernel(const float* __restrict__ O_part,
                                                          const float* __restrict__ l_part,
                                                          float* __restrict__ out) {
    __shared__ float Ls[32];
    const int qb_i = blockIdx.x >> 2;
    const int q4 = blockIdx.x & 3;
    const int t = threadIdx.x;
    const int np = (qb_i >> 2) + 1;
    const int base = part_base(qb_i);

    if (t < 32) {
        float s = 0.0f;
        for (int p = 0; p < np; ++p)
            s += __builtin_nontemporal_load(l_part + (base + p) * 128 + q4 * 32 + t);
        Ls[t] = s;
    }
    __syncthreads();

#pragma unroll
    for (int u = 0; u < 2; ++u) {
        const int e = q4 * 2048 + (t * 2 + u) * 4;
        const int row = (t * 2 + u) >> 4;
        f4v acc = {0.f, 0.f, 0.f, 0.f};
        for (int p = 0; p < np; ++p)
            acc += __builtin_nontemporal_load((const f4v*)(O_part + (size_t)(base + p) * 8192 + e));
        acc *= (1.0f / Ls[row]);
        *(f4v*)(out + qb_i * 8192 + e) = acc;
    }
}

extern "C" void kernel_launch(void* const* d_in, const int* in_sizes, int n_in,
                              void* d_out, int out_size, void* d_ws, size_t ws_size,
                              hipStream_t stream) {
    const float* x  = (const float*)d_in[0];
    const float* wq = (const float*)d_in[1];
    const float* wk = (const float*)d_in[2];
    const float* wv = (const float*)d_in[3];
    float* out = (float*)d_out;

    char* ws = (char*)d_ws;
    unsigned short* qb = (unsigned short*)(ws);               // 1,048,576 B
    unsigned short* kb = (unsigned short*)(ws + 1048576);     // 1,048,576 B
    unsigned short* vt = (unsigned short*)(ws + 2097152);     // 1,048,576 B (V^T [64][8192])
    float* O_part = (float*)(ws + 3145728);                   // 544*8192*4 = 17,825,792 B
    float* l_part = (float*)(ws + 20971520);                  // 544*128*4 = 278,528 B
    // total ws: 21,250,048 B

    proj_kernel<<<dim3(128, 3), 256, 0, stream>>>(x, wq, wk, wv, qb, kb, vt);
    attn_kernel<<<dim3(16, 64), 256, 0, stream>>>(qb, kb, vt, O_part, l_part);
    attn_reduce_kernel<<<256, 256, 0, stream>>>(O_part, l_part, out);
}